// Round 7
// baseline (83.972 us; speedup 1.0000x reference)
//
#include <hip/hip_runtime.h>
#include <hip/hip_fp16.h>

#define N_KER 64
#define K_PTS 16
#define LOG2E 1.44269504088896340736f

// ============================================================================
// out[i][m] = (1/128) * (S[i][m] + S[a][m] + S[b][m] + S[c][m]),
// S[q][m] = sum_l exp(-||g_q - k[m][l]||^2)  (phase1: 51.2M exps, issue-bound;
// phase2: memory-bound gather-add of f16 S rows).
// R7: phase1 staging rebuilt — raw kern loaded COALESCED into LDS then
// repacked (R6 staged with stride-192B scattered global loads, ~64 cache
// lines per instruction, repeated in 3125 blocks). Blocks are now 1024
// threads (64 points) so staging is amortized 4x (782 blocks).
// ============================================================================

// ---- Phase 1: S[q][m] in f16; lane = m; 16 waves x 4 points per block ----
__global__ __launch_bounds__(1024, 8) void corr_phase1(
    const float* __restrict__ normal,
    const float* __restrict__ kern,
    __half*      __restrict__ S,
    int n)
{
    __shared__ float  kraw[N_KER * K_PTS * 3];   // 12 KB raw copy
    __shared__ float4 ksp[K_PTS * N_KER];        // 16 KB packed [l][m]

    const int tid = threadIdx.x;

    // coalesced raw stage: 3 x 4KB contiguous
    kraw[tid]        = kern[tid];
    kraw[tid + 1024] = kern[tid + 1024];
    kraw[tid + 2048] = kern[tid + 2048];
    __syncthreads();

    // repack from LDS (once per block; bank conflicts here are ~100 cyc total)
    {
        int m = tid & 63, l = tid >> 6;
        const float* kp = &kraw[(m * K_PTS + l) * 3];
        float x = kp[0], y = kp[1], z = kp[2];
        ksp[l * N_KER + m] = make_float4(2.0f * LOG2E * x,
                                         2.0f * LOG2E * y,
                                         2.0f * LOG2E * z,
                                         -LOG2E * (x * x + y * y + z * z));
    }
    __syncthreads();

    const int wave = tid >> 6;                    // 0..15
    const int m    = tid & 63;
    const int q0   = blockIdx.x * 64 + wave * 4;  // 4 points per wave

    float gx[4], gy[4], gz[4], ea[4], acc[4];
    #pragma unroll
    for (int p = 0; p < 4; ++p) {
        int q = min(q0 + p, n - 1);
        float x = normal[q * 3 + 0];   // wave-uniform -> single line per load
        float y = normal[q * 3 + 1];
        float z = normal[q * 3 + 2];
        gx[p] = x; gy[p] = y; gz[p] = z;
        ea[p] = __builtin_amdgcn_exp2f(-LOG2E * (x * x + y * y + z * z));
        acc[p] = 0.0f;
    }

    // 16 l-steps x 4 points: 1 ds_read_b128 -> 4 exps. unroll 4 keeps VGPR
    // under the 64 boundary (R3 lesson: crossing it halves occupancy).
    #pragma unroll 4
    for (int l = 0; l < K_PTS; ++l) {
        float4 k4 = ksp[l * N_KER + m];
        #pragma unroll
        for (int p = 0; p < 4; ++p)
            acc[p] += __builtin_amdgcn_exp2f(
                fmaf(gx[p], k4.x, fmaf(gy[p], k4.y, fmaf(gz[p], k4.z, k4.w))));
    }

    #pragma unroll
    for (int p = 0; p < 4; ++p)
        if (q0 + p < n)                 // 128B/wave coalesced f16 store
            S[(size_t)(q0 + p) * N_KER + m] = __float2half(ea[p] * acc[p]);
}

// ---- Phase 2: out = (S[i]+S[a]+S[b]+S[c]) / 128; __half2 per thread ----
// t>>5 = point, t&31 = half2 slot; each gathered row = 128B contiguous.
__global__ __launch_bounds__(256) void corr_phase2(
    const __half2* __restrict__ S2,
    const int*     __restrict__ neighbour,
    float2*        __restrict__ out2,
    int n)
{
    int t = blockIdx.x * 256 + threadIdx.x;
    int total2 = n * (N_KER / 2);
    if (t >= total2) return;
    int i = t >> 5;
    int h = t & 31;
    int a = neighbour[i * 3 + 0];
    int b = neighbour[i * 3 + 1];
    int c = neighbour[i * 3 + 2];
    float2 s0 = __half22float2(S2[t]);
    float2 s1 = __half22float2(S2[(size_t)a * 32 + h]);
    float2 s2 = __half22float2(S2[(size_t)b * 32 + h]);
    float2 s3 = __half22float2(S2[(size_t)c * 32 + h]);
    float2 r;
    r.x = (s0.x + s1.x + s2.x + s3.x) * (1.0f / 128.0f);
    r.y = (s0.y + s1.y + s2.y + s3.y) * (1.0f / 128.0f);
    out2[t] = r;
}

// ---- Fallback (R4 fused kernel, proven) if ws too small ----
__global__ __launch_bounds__(256, 8) void corr_fused(
    const float* __restrict__ normal,
    const int*   __restrict__ neighbour,
    const float* __restrict__ kern,
    float*       __restrict__ out,
    int n)
{
    __shared__ float4 ksp[K_PTS * N_KER];
    const int tid = threadIdx.x;
    #pragma unroll
    for (int it = 0; it < 4; ++it) {
        int j = it * 256 + tid;
        int m = j & 63;
        int l = j >> 6;
        const float* kp = kern + (m * K_PTS + l) * 3;
        float x = kp[0], y = kp[1], z = kp[2];
        ksp[l * N_KER + m] = make_float4(2.0f * LOG2E * x, 2.0f * LOG2E * y,
                                         2.0f * LOG2E * z,
                                         -LOG2E * (x * x + y * y + z * z));
    }
    __syncthreads();
    const int wave = tid >> 6;
    const int m    = tid & 63;
    const int i    = blockIdx.x * 4 + wave;
    if (i >= n) return;
    const int ia = neighbour[i * 3 + 0];
    const int ib = neighbour[i * 3 + 1];
    const int ic = neighbour[i * 3 + 2];
    int idxs[4] = { i, ia, ib, ic };
    float gx[4], gy[4], gz[4], ea[4], acc[4];
    #pragma unroll
    for (int p = 0; p < 4; ++p) {
        int q = idxs[p];
        float x = normal[q * 3 + 0];
        float y = normal[q * 3 + 1];
        float z = normal[q * 3 + 2];
        gx[p] = x; gy[p] = y; gz[p] = z;
        ea[p] = __builtin_amdgcn_exp2f(-LOG2E * (x * x + y * y + z * z));
        acc[p] = 0.0f;
    }
    #pragma unroll 4
    for (int l = 0; l < K_PTS; ++l) {
        float4 k4 = ksp[l * N_KER + m];
        #pragma unroll
        for (int p = 0; p < 4; ++p)
            acc[p] += __builtin_amdgcn_exp2f(
                fmaf(gx[p], k4.x, fmaf(gy[p], k4.y, fmaf(gz[p], k4.z, k4.w))));
    }
    float s = ea[0] * acc[0] + ea[1] * acc[1] + ea[2] * acc[2] + ea[3] * acc[3];
    out[(size_t)i * N_KER + m] = s * (1.0f / 128.0f);
}

extern "C" void kernel_launch(void* const* d_in, const int* in_sizes, int n_in,
                              void* d_out, int out_size, void* d_ws, size_t ws_size,
                              hipStream_t stream) {
    const float* normal    = (const float*)d_in[0];
    const int*   neighbour = (const int*)d_in[1];
    const float* kern      = (const float*)d_in[2];
    float*       out       = (float*)d_out;

    int n = in_sizes[0] / 3;
    size_t need = (size_t)n * N_KER * sizeof(__half);

    if (ws_size >= need) {
        __half* S = (__half*)d_ws;
        int blocks1 = (n + 63) / 64;                   // 64 points per block
        corr_phase1<<<blocks1, 1024, 0, stream>>>(normal, kern, S, n);
        int total2  = n * (N_KER / 2);
        int blocks2 = (total2 + 255) / 256;
        corr_phase2<<<blocks2, 256, 0, stream>>>((const __half2*)S, neighbour,
                                                 (float2*)out, n);
    } else {
        int blocks = (n + 3) / 4;
        corr_fused<<<blocks, 256, 0, stream>>>(normal, neighbour, kern, out, n);
    }
}

// Round 8
// 78.742 us; speedup vs baseline: 1.0664x; 1.0664x over previous
//
#include <hip/hip_runtime.h>

#define N_KER 64
#define K_PTS 16
#define LOG2E 1.44269504088896340736f

// ============================================================================
// out[i][m] = (1/128) * (S[i][m] + S[a][m] + S[b][m] + S[c][m]),
// S[q][m] = sum_l exp(-||g_q - k[m][l]||^2)   (phase1: 51.2M exps, issue-bound)
// R8: S stored as uint8 (S in (0,16], step 16/255 -> out err <= 9.8e-4 worst,
// threshold 3.4e-3). Rows shrink 256B(f32)->128B(f16,R6)->64B: 3.2 MB table
// ~fits one XCD L2, phase2 gather traffic halves again, dequant is exact
// integer adds + one mul. Phase1 is EXACTLY R6's (best measured, 81.6 us);
// R7's staging rework regressed and is reverted — one variable this round.
// ============================================================================

// ---- Phase 1: S[q][m] u8; lane = m; 4 waves x 4 points per block ----
__global__ __launch_bounds__(256, 8) void corr_phase1(
    const float*   __restrict__ normal,
    const float*   __restrict__ kern,
    unsigned char* __restrict__ S,
    int n)
{
    __shared__ float4 ksp[K_PTS * N_KER];   // 16 KB [l][m], conflict-free (R3+)

    const int tid = threadIdx.x;
    #pragma unroll
    for (int it = 0; it < 4; ++it) {
        int j = it * 256 + tid;            // 0..1023 -> (l,m)
        int m = j & 63;
        int l = j >> 6;
        const float* kp = kern + (m * K_PTS + l) * 3;
        float x = kp[0], y = kp[1], z = kp[2];
        ksp[l * N_KER + m] = make_float4(2.0f * LOG2E * x,
                                         2.0f * LOG2E * y,
                                         2.0f * LOG2E * z,
                                         -LOG2E * (x * x + y * y + z * z));
    }
    __syncthreads();

    const int wave = tid >> 6;
    const int m    = tid & 63;
    const int q0   = blockIdx.x * 16 + wave * 4;   // 4 points per wave

    float gx[4], gy[4], gz[4], ea[4], acc[4];
    #pragma unroll
    for (int p = 0; p < 4; ++p) {
        int q = min(q0 + p, n - 1);
        float x = normal[q * 3 + 0];    // wave-uniform -> broadcast loads
        float y = normal[q * 3 + 1];
        float z = normal[q * 3 + 2];
        gx[p] = x; gy[p] = y; gz[p] = z;
        ea[p] = __builtin_amdgcn_exp2f(-LOG2E * (x * x + y * y + z * z));
        acc[p] = 0.0f;
    }

    // 16 l-steps x 4 points: 1 ds_read_b128 -> 4 exps; unroll 4 keeps
    // VGPR < 64 (R3 lesson: crossing 64 halves occupancy).
    #pragma unroll 4
    for (int l = 0; l < K_PTS; ++l) {
        float4 k4 = ksp[l * N_KER + m];
        #pragma unroll
        for (int p = 0; p < 4; ++p)
            acc[p] += __builtin_amdgcn_exp2f(
                fmaf(gx[p], k4.x, fmaf(gy[p], k4.y, fmaf(gz[p], k4.z, k4.w))));
    }

    // u8 quantize: v in (0,16], q = v*255/16 + 0.5 truncated; 64 contiguous
    // byte stores per wave per point -> one 64B txn.
    const float QS = 255.0f / 16.0f;
    #pragma unroll
    for (int p = 0; p < 4; ++p)
        if (q0 + p < n) {
            float v = ea[p] * acc[p];
            S[(size_t)(q0 + p) * N_KER + m] = (unsigned char)(v * QS + 0.5f);
        }
}

// ---- Phase 2: 16 threads/point; each thread: 4 u32 row-word loads,
// exact integer sums per byte lane, one dequant mul, float4 store. ----
__global__ __launch_bounds__(256) void corr_phase2(
    const unsigned int* __restrict__ S4,     // u8 rows viewed as 16 u32 words
    const int*          __restrict__ neighbour,
    float4*             __restrict__ out4,
    int n)
{
    int t = blockIdx.x * 256 + threadIdx.x;  // word index == i*16 + h
    if (t >= n * 16) return;
    int i = t >> 4;
    int a = neighbour[i * 3 + 0];
    int b = neighbour[i * 3 + 1];
    int c = neighbour[i * 3 + 2];
    int h = t & 15;
    unsigned int w0 = S4[t];                 // self: coalesced
    unsigned int w1 = S4[a * 16 + h];        // 64B row segments, L2-resident
    unsigned int w2 = S4[b * 16 + h];
    unsigned int w3 = S4[c * 16 + h];
    const float DQ = (16.0f / 255.0f) / 128.0f;
    float4 r;
    r.x = (float)(( w0        & 255u) + ( w1        & 255u) +
                  ( w2        & 255u) + ( w3        & 255u)) * DQ;
    r.y = (float)(((w0 >>  8) & 255u) + ((w1 >>  8) & 255u) +
                  ((w2 >>  8) & 255u) + ((w3 >>  8) & 255u)) * DQ;
    r.z = (float)(((w0 >> 16) & 255u) + ((w1 >> 16) & 255u) +
                  ((w2 >> 16) & 255u) + ((w3 >> 16) & 255u)) * DQ;
    r.w = (float)(( w0 >> 24        ) + ( w1 >> 24        ) +
                  ( w2 >> 24        ) + ( w3 >> 24        )) * DQ;
    out4[t] = r;
}

// ---- Fallback (R4 fused kernel, proven) if ws too small ----
__global__ __launch_bounds__(256, 8) void corr_fused(
    const float* __restrict__ normal,
    const int*   __restrict__ neighbour,
    const float* __restrict__ kern,
    float*       __restrict__ out,
    int n)
{
    __shared__ float4 ksp[K_PTS * N_KER];
    const int tid = threadIdx.x;
    #pragma unroll
    for (int it = 0; it < 4; ++it) {
        int j = it * 256 + tid;
        int m = j & 63;
        int l = j >> 6;
        const float* kp = kern + (m * K_PTS + l) * 3;
        float x = kp[0], y = kp[1], z = kp[2];
        ksp[l * N_KER + m] = make_float4(2.0f * LOG2E * x, 2.0f * LOG2E * y,
                                         2.0f * LOG2E * z,
                                         -LOG2E * (x * x + y * y + z * z));
    }
    __syncthreads();
    const int wave = tid >> 6;
    const int m    = tid & 63;
    const int i    = blockIdx.x * 4 + wave;
    if (i >= n) return;
    const int ia = neighbour[i * 3 + 0];
    const int ib = neighbour[i * 3 + 1];
    const int ic = neighbour[i * 3 + 2];
    int idxs[4] = { i, ia, ib, ic };
    float gx[4], gy[4], gz[4], ea[4], acc[4];
    #pragma unroll
    for (int p = 0; p < 4; ++p) {
        int q = idxs[p];
        float x = normal[q * 3 + 0];
        float y = normal[q * 3 + 1];
        float z = normal[q * 3 + 2];
        gx[p] = x; gy[p] = y; gz[p] = z;
        ea[p] = __builtin_amdgcn_exp2f(-LOG2E * (x * x + y * y + z * z));
        acc[p] = 0.0f;
    }
    #pragma unroll 4
    for (int l = 0; l < K_PTS; ++l) {
        float4 k4 = ksp[l * N_KER + m];
        #pragma unroll
        for (int p = 0; p < 4; ++p)
            acc[p] += __builtin_amdgcn_exp2f(
                fmaf(gx[p], k4.x, fmaf(gy[p], k4.y, fmaf(gz[p], k4.z, k4.w))));
    }
    float s = ea[0] * acc[0] + ea[1] * acc[1] + ea[2] * acc[2] + ea[3] * acc[3];
    out[(size_t)i * N_KER + m] = s * (1.0f / 128.0f);
}

extern "C" void kernel_launch(void* const* d_in, const int* in_sizes, int n_in,
                              void* d_out, int out_size, void* d_ws, size_t ws_size,
                              hipStream_t stream) {
    const float* normal    = (const float*)d_in[0];
    const int*   neighbour = (const int*)d_in[1];
    const float* kern      = (const float*)d_in[2];
    float*       out       = (float*)d_out;

    int n = in_sizes[0] / 3;
    size_t need = (size_t)n * N_KER;               // u8 table bytes

    if (ws_size >= need) {
        unsigned char* S = (unsigned char*)d_ws;
        int blocks1 = (n + 15) / 16;               // 4 q/wave, 4 waves (R6 cfg)
        corr_phase1<<<blocks1, 256, 0, stream>>>(normal, kern, S, n);
        int blocks2 = (n * 16 + 255) / 256;
        corr_phase2<<<blocks2, 256, 0, stream>>>((const unsigned int*)S,
                                                 neighbour, (float4*)out, n);
    } else {
        int blocks = (n + 3) / 4;
        corr_fused<<<blocks, 256, 0, stream>>>(normal, neighbour, kern, out, n);
    }
}